// Round 6
// baseline (521.203 us; speedup 1.0000x reference)
//
#include <hip/hip_runtime.h>

// out[N,32] = segment_sum(edge_val[e] * weight[edge_col[e], :], edge_row[e]) + bias
// R6: bucket pipeline (zero -> hist -> scan -> bin -> acc). Fix vs R3: k_acc2
// loads records COALESCED into registers (dwordx2/lane), shfl-redistributes,
// and processes with a fully-unrolled 32-round loop (~32 weight loads in
// flight). R3's k_acc read records as 8B broadcast loads w/ 64B stride ->
// 80MB latency-bound fetch @270GB/s = 346us. Global fp atomics eliminated
// (R5 proved they write through TCC: WRITE==E*128B regardless of locality).
// Record: hi32 = val bits, lo32 = col | (row_local << 17). Needs N <= 131072.

#define FEAT 32
#define RB 128          // rows per bucket -> 16KB LDS accumulator
#define RB_BITS 7
#define MAXB 1024
#define BINB 128        // blocks for hist/bin (runs ~16 recs = 128B)

// ---------------- fallback (R1 baseline, known-good) ----------------
__global__ __launch_bounds__(256) void gnn_init_out(
    const float* __restrict__ bias, float* __restrict__ out, int total) {
    int i = blockIdx.x * blockDim.x + threadIdx.x;
    if (i < total) out[i] = bias[i & (FEAT - 1)];
}

__global__ __launch_bounds__(256) void gnn_scatter(
    const int* __restrict__ edge_row, const int* __restrict__ edge_col,
    const float* __restrict__ edge_val, const float* __restrict__ weight,
    float* __restrict__ out, int num_edges) {
    long long t = (long long)blockIdx.x * blockDim.x + threadIdx.x;
    int e = (int)(t >> 5);
    int f = (int)(t & (FEAT - 1));
    if (e < num_edges) {
        atomicAdd(out + edge_row[e] * FEAT + f,
                  edge_val[e] * weight[edge_col[e] * FEAT + f]);
    }
}

// ---------------- R6 pipeline ----------------
__global__ __launch_bounds__(256) void k_zero(int* __restrict__ p, int n) {
    int i = blockIdx.x * blockDim.x + threadIdx.x;
    if (i < n) p[i] = 0;
}

__global__ __launch_bounds__(256) void k_hist(
    const int* __restrict__ edge_row, int* __restrict__ counts,
    int num_edges, int B, int chunk) {
    __shared__ int lc[MAXB];
    for (int i = threadIdx.x; i < B; i += 256) lc[i] = 0;
    __syncthreads();
    int base = blockIdx.x * chunk;
    int end = min(base + chunk, num_edges);
    for (int i = base + threadIdx.x; i < end; i += 256)
        atomicAdd(&lc[edge_row[i] >> RB_BITS], 1);
    __syncthreads();
    for (int i = threadIdx.x; i < B; i += 256)
        if (lc[i]) atomicAdd(&counts[i], lc[i]);
}

__global__ __launch_bounds__(256) void k_scan(
    const int* __restrict__ counts, int* __restrict__ start,
    int* __restrict__ cursor, int B) {
    __shared__ int tsum[256];
    int b0 = threadIdx.x * 4;
    int v0 = (b0 + 0 < B) ? counts[b0 + 0] : 0;
    int v1 = (b0 + 1 < B) ? counts[b0 + 1] : 0;
    int v2 = (b0 + 2 < B) ? counts[b0 + 2] : 0;
    int v3 = (b0 + 3 < B) ? counts[b0 + 3] : 0;
    int s = v0 + v1 + v2 + v3;
    tsum[threadIdx.x] = s;
    __syncthreads();
    #pragma unroll
    for (int off = 1; off < 256; off <<= 1) {
        int t = (threadIdx.x >= off) ? tsum[threadIdx.x - off] : 0;
        __syncthreads();
        tsum[threadIdx.x] += t;
        __syncthreads();
    }
    int ex = tsum[threadIdx.x] - s;
    if (b0 + 0 < B) { start[b0 + 0] = ex; cursor[b0 + 0] = ex; } ex += v0;
    if (b0 + 1 < B) { start[b0 + 1] = ex; cursor[b0 + 1] = ex; } ex += v1;
    if (b0 + 2 < B) { start[b0 + 2] = ex; cursor[b0 + 2] = ex; } ex += v2;
    if (b0 + 3 < B) { start[b0 + 3] = ex; cursor[b0 + 3] = ex; }
}

// LDS-staged bucket scatter: one contiguous run per (block,bucket).
__global__ __launch_bounds__(256) void k_bin(
    const int* __restrict__ edge_row, const int* __restrict__ edge_col,
    const float* __restrict__ edge_val, int* __restrict__ cursor,
    unsigned long long* __restrict__ buf, int num_edges, int B, int chunk) {
    __shared__ int lc[MAXB];
    __shared__ int lbase[MAXB];
    for (int i = threadIdx.x; i < B; i += 256) lc[i] = 0;
    __syncthreads();
    int base = blockIdx.x * chunk;
    int end = min(base + chunk, num_edges);
    for (int i = base + threadIdx.x; i < end; i += 256)
        atomicAdd(&lc[edge_row[i] >> RB_BITS], 1);
    __syncthreads();
    for (int i = threadIdx.x; i < B; i += 256) {
        int c = lc[i];
        if (c) lbase[i] = atomicAdd(&cursor[i], c);
        lc[i] = 0;
    }
    __syncthreads();
    for (int i = base + threadIdx.x; i < end; i += 256) {
        int r = edge_row[i];
        int b = r >> RB_BITS;
        int off = atomicAdd(&lc[b], 1);
        unsigned long long rec =
            ((unsigned long long)__float_as_uint(edge_val[i]) << 32) |
            (unsigned int)(edge_col[i] | ((r & (RB - 1)) << 17));
        buf[lbase[b] + off] = rec;
    }
}

// One block per bucket. Coalesced register staging of 64 records/wave, shfl
// redistribute, 2 records/round (half-waves), unrolled 32 rounds -> deep MLP.
__global__ __launch_bounds__(256) void k_acc2(
    const unsigned long long* __restrict__ buf,
    const int* __restrict__ start, const int* __restrict__ counts,
    const float* __restrict__ weight, const float* __restrict__ bias,
    float* __restrict__ out, int N) {
    __shared__ float accs[RB * FEAT];  // 16 KB
    for (int i = threadIdx.x; i < RB * FEAT; i += 256) accs[i] = 0.f;
    __syncthreads();
    const int b = blockIdx.x;
    const int s = start[b];
    const int c = counts[b];
    const int lane = threadIdx.x & 63;
    const int half = lane >> 5;        // which record of the pair this half takes
    const int f = lane & 31;
    const int wv = threadIdx.x >> 6;   // wave id 0..3

    for (int base = wv * 64; base < c; base += 256) {
        int idx = base + lane;
        unsigned long long rec = 0;    // OOB: val=0, col=0, rl=0 (guarded below)
        if (idx < c) rec = buf[s + idx];   // coalesced dwordx2, 512B/wave
        unsigned int lo = (unsigned int)rec;
        float val = __uint_as_float((unsigned int)(rec >> 32));
        int col = lo & 0x1FFFF;
        int rl  = (lo >> 17) & (RB - 1);
        int nrec = min(64, c - base);
        #pragma unroll
        for (int t = 0; t < 32; ++t) {
            int j = 2 * t + half;      // half 0 -> even record, half 1 -> odd
            int   cj  = __shfl(col, j);
            float vj  = __shfl(val, j);
            int   rlj = __shfl(rl, j);
            if (j < nrec) {
                float w = weight[(size_t)cj * FEAT + f];  // 128B coalesced/half
                atomicAdd(&accs[rlj * FEAT + f], vj * w); // banks 0-31, 2 lanes/bank
            }
        }
    }
    __syncthreads();
    const int gid = threadIdx.x >> 5;
    const int ff = threadIdx.x & 31;
    const float bf = bias[ff];
    const int rbase = b * RB;
    for (int r = gid; r < RB; r += 8) {
        int row = rbase + r;
        if (row < N) out[row * FEAT + ff] = accs[r * FEAT + ff] + bf;
    }
}

extern "C" void kernel_launch(void* const* d_in, const int* in_sizes, int n_in,
                              void* d_out, int out_size, void* d_ws, size_t ws_size,
                              hipStream_t stream) {
    const int*   edge_row = (const int*)d_in[0];
    const int*   edge_col = (const int*)d_in[1];
    const float* edge_val = (const float*)d_in[2];
    const float* weight   = (const float*)d_in[3];
    const float* bias     = (const float*)d_in[4];
    float* out = (float*)d_out;

    const int E = in_sizes[0];
    const int N = out_size / FEAT;
    const int B = (N + RB - 1) / RB;

    // ws layout: counts[B] | start[B] | cursor[B] | pad | buf[E] u64
    size_t buf_off = (((size_t)3 * B) * 4 + 15) & ~(size_t)15;
    size_t need = buf_off + (size_t)E * 8;

    if (ws_size < need || B > MAXB || N > (1 << 17) || E <= 0) {  // fallback: R1
        gnn_init_out<<<(out_size + 255) / 256, 256, 0, stream>>>(bias, out, out_size);
        long long threads = (long long)E * FEAT;
        gnn_scatter<<<(int)((threads + 255) / 256), 256, 0, stream>>>(
            edge_row, edge_col, edge_val, weight, out, E);
        return;
    }

    int* counts = (int*)d_ws;
    int* start  = counts + B;
    int* cursor = start + B;
    unsigned long long* buf = (unsigned long long*)((char*)d_ws + buf_off);

    const int chunk = (E + BINB - 1) / BINB;

    k_zero<<<(B + 255) / 256, 256, 0, stream>>>(counts, B);
    k_hist<<<BINB, 256, 0, stream>>>(edge_row, counts, E, B, chunk);
    k_scan<<<1, 256, 0, stream>>>(counts, start, cursor, B);
    k_bin<<<BINB, 256, 0, stream>>>(edge_row, edge_col, edge_val,
                                    cursor, buf, E, B, chunk);
    k_acc2<<<B, 256, 0, stream>>>(buf, start, counts, weight, bias, out, N);
}